// Round 1
// baseline (1631.413 us; speedup 1.0000x reference)
//
#include <hip/hip_runtime.h>

// ---------------------------------------------------------------------------
// NGCF forward, algebraically refactored:
//   per layer: S[v] = sum_{e: dst=v} w_e * x[src_e],  c[v] = sum w_e
//   out[v] = leakyrelu( (S+x)@W1 + (x*S)@W2 + (c+1)*b1 + c*b2 ), row-L2-norm
//   xui[b] = sum_l dot(x_l[user_b], x_l[NUM_USERS+pos_b])
// Edge buckets (CSR by dst) + c built once per call; reused for 3 layers.
// ---------------------------------------------------------------------------

__global__ __launch_bounds__(256) void init_x_kernel(
    const float* __restrict__ Gu, const float* __restrict__ Gi,
    float* __restrict__ x, int nu4, int nt4) {
  int i = blockIdx.x * 256 + threadIdx.x;
  if (i >= nt4) return;
  float4 v = (i < nu4) ? ((const float4*)Gu)[i] : ((const float4*)Gi)[i - nu4];
  ((float4*)x)[i] = v;
}

__global__ __launch_bounds__(256) void hist_kernel(
    const int* __restrict__ dst, const float* __restrict__ w,
    int* __restrict__ counts, float* __restrict__ cw, int E) {
  int e = blockIdx.x * 256 + threadIdx.x;
  if (e >= E) return;
  int d = dst[e];
  atomicAdd(&counts[d], 1);
  atomicAdd(&cw[d], w[e]);
}

// single-block scan: 1024 threads, each owns a contiguous chunk
__global__ __launch_bounds__(1024) void scan_kernel(
    const int* __restrict__ counts, int* __restrict__ starts,
    int* __restrict__ cursor, int n) {
  __shared__ int bs[1024];
  int tid = threadIdx.x;
  int per = (n + 1023) >> 10;
  int lo = min(tid * per, n);
  int hi = min(lo + per, n);
  int s = 0;
  for (int i = lo; i < hi; ++i) s += counts[i];
  bs[tid] = s;
  __syncthreads();
  int incl = s;
  for (int off = 1; off < 1024; off <<= 1) {
    int t = (tid >= off) ? bs[tid - off] : 0;
    __syncthreads();
    incl += t;
    bs[tid] = incl;
    __syncthreads();
  }
  int run = incl - s;  // exclusive prefix of this chunk
  for (int i = lo; i < hi; ++i) {
    starts[i] = run;
    cursor[i] = run;
    run += counts[i];
  }
}

__global__ __launch_bounds__(256) void place_kernel(
    const int* __restrict__ src, const int* __restrict__ dst,
    const float* __restrict__ w, int* __restrict__ cursor,
    int* __restrict__ ssrc, float* __restrict__ sw, int E) {
  int e = blockIdx.x * 256 + threadIdx.x;
  if (e >= E) return;
  int p = atomicAdd(&cursor[dst[e]], 1);
  ssrc[p] = src[e];
  sw[p] = w[e];
}

// one wave per batch element; lane = dim; accumulate per-layer dot into out
__global__ __launch_bounds__(256) void dot_kernel(
    const float* __restrict__ x, const int* __restrict__ user,
    const int* __restrict__ pos, float* __restrict__ out,
    int batch, int nusers, int accumulate) {
  int b = blockIdx.x * 4 + (threadIdx.x >> 6);
  int lane = threadIdx.x & 63;
  if (b >= batch) return;
  int u = user[b];
  int p = nusers + pos[b];
  float val = x[u * 64 + lane] * x[p * 64 + lane];
#pragma unroll
  for (int m = 1; m < 64; m <<= 1) val += __shfl_xor(val, m, 64);
  if (lane == 0) out[b] = accumulate ? (out[b] + val) : val;
}

// fused: gather-sum S (CSR buckets), matvec with W cols in VGPRs,
// leaky-relu, row L2 normalize. wave per node, lane = dim.
__global__ __launch_bounds__(256) void layer_kernel(
    const float* __restrict__ xc, float* __restrict__ xn,
    const float* __restrict__ W1, const float* __restrict__ b1,
    const float* __restrict__ W2, const float* __restrict__ b2,
    const int* __restrict__ starts, const int* __restrict__ degs,
    const float* __restrict__ cw, const int* __restrict__ ssrc,
    const float* __restrict__ sw, int nnodes) {
  const int lane = threadIdx.x & 63;
  const int wid = threadIdx.x >> 6;
  __shared__ float ash[4][64];
  __shared__ float gsh[4][64];

  // lane k holds column k of W1 and W2 (register-resident weights)
  float w1c[64], w2c[64];
#pragma unroll
  for (int j = 0; j < 64; ++j) {
    w1c[j] = W1[j * 64 + lane];
    w2c[j] = W2[j * 64 + lane];
  }
  const float b1k = b1[lane];
  const float b2k = b2[lane];

  const int wstride = gridDim.x * 4;
  for (int v = blockIdx.x * 4 + wid; v < nnodes; v += wstride) {
    const float xk = xc[v * 64 + lane];
    int s0 = __builtin_amdgcn_readfirstlane(starts[v]);
    int dg = __builtin_amdgcn_readfirstlane(degs[v]);
    int end = s0 + dg;
    float S = 0.f;
    int e = s0;
    // unroll-4 so 4 gather loads are in flight per wave
    for (; e + 4 <= end; e += 4) {
      int i0 = ssrc[e] * 64, i1 = ssrc[e + 1] * 64;
      int i2 = ssrc[e + 2] * 64, i3 = ssrc[e + 3] * 64;
      float w0 = sw[e], w1 = sw[e + 1], w2 = sw[e + 2], w3 = sw[e + 3];
      float v0 = xc[i0 + lane], v1 = xc[i1 + lane];
      float v2 = xc[i2 + lane], v3 = xc[i3 + lane];
      S = fmaf(w0, v0, S);
      S = fmaf(w1, v1, S);
      S = fmaf(w2, v2, S);
      S = fmaf(w3, v3, S);
    }
    for (; e < end; ++e) S = fmaf(sw[e], xc[ssrc[e] * 64 + lane], S);

    ash[wid][lane] = S + xk;
    gsh[wid][lane] = S * xk;
    asm volatile("" ::: "memory");  // order LDS write before b128 reads

    float acc1 = 0.f, acc2 = 0.f;
#pragma unroll
    for (int q = 0; q < 16; ++q) {
      float4 av, gv;
      __builtin_memcpy(&av, &ash[wid][4 * q], 16);  // broadcast ds_read_b128
      __builtin_memcpy(&gv, &gsh[wid][4 * q], 16);
      acc1 = fmaf(av.x, w1c[4 * q + 0], acc1);
      acc1 = fmaf(av.y, w1c[4 * q + 1], acc1);
      acc1 = fmaf(av.z, w1c[4 * q + 2], acc1);
      acc1 = fmaf(av.w, w1c[4 * q + 3], acc1);
      acc2 = fmaf(gv.x, w2c[4 * q + 0], acc2);
      acc2 = fmaf(gv.y, w2c[4 * q + 1], acc2);
      acc2 = fmaf(gv.z, w2c[4 * q + 2], acc2);
      acc2 = fmaf(gv.w, w2c[4 * q + 3], acc2);
    }
    const float cv = cw[v];
    float pre = acc1 + acc2 + (cv + 1.0f) * b1k + cv * b2k;
    float o = (pre > 0.0f) ? pre : 0.01f * pre;  // leaky relu, slope 0.01
    float ss = o * o;
#pragma unroll
    for (int m = 1; m < 64; m <<= 1) ss += __shfl_xor(ss, m, 64);
    float nrm = sqrtf(ss);
    xn[v * 64 + lane] = o / fmaxf(nrm, 1e-12f);
  }
}

extern "C" void kernel_launch(void* const* d_in, const int* in_sizes, int n_in,
                              void* d_out, int out_size, void* d_ws, size_t ws_size,
                              hipStream_t stream) {
  const float* Gu = (const float*)d_in[0];
  const float* Gi = (const float*)d_in[1];
  const float* W1 = (const float*)d_in[2];
  const float* b1 = (const float*)d_in[3];
  const float* W2 = (const float*)d_in[4];
  const float* b2 = (const float*)d_in[5];
  const float* ew = (const float*)d_in[6];
  const int* esrc = (const int*)d_in[7];
  const int* edst = (const int*)d_in[8];
  const int* user = (const int*)d_in[9];
  const int* pos = (const int*)d_in[10];
  float* out = (float*)d_out;

  const int NU = in_sizes[0] / 64;
  const int NI = in_sizes[1] / 64;
  const int N = NU + NI;
  const int E = in_sizes[6];
  const int B = in_sizes[9];

  char* ws = (char*)d_ws;
  size_t off = 0;
  auto carve = [&](size_t bytes) -> void* {
    void* p = ws + off;
    off = (off + bytes + 255) & ~(size_t)255;
    return p;
  };
  float* x0 = (float*)carve((size_t)N * 64 * 4);
  float* x1 = (float*)carve((size_t)N * 64 * 4);
  int* ssrc = (int*)carve((size_t)E * 4);
  float* sw = (float*)carve((size_t)E * 4);
  int* startsA = (int*)carve((size_t)N * 4);
  int* cursor = (int*)carve((size_t)N * 4);
  int* counts = (int*)carve((size_t)N * 4);
  float* cw = (float*)carve((size_t)N * 4);

  hipMemsetAsync(counts, 0, (size_t)N * 4, stream);
  hipMemsetAsync(cw, 0, (size_t)N * 4, stream);

  hist_kernel<<<(E + 255) / 256, 256, 0, stream>>>(edst, ew, counts, cw, E);
  scan_kernel<<<1, 1024, 0, stream>>>(counts, startsA, cursor, N);
  place_kernel<<<(E + 255) / 256, 256, 0, stream>>>(esrc, edst, ew, cursor, ssrc, sw, E);

  int nt4 = N * 64 / 4;
  int nu4 = NU * 64 / 4;
  init_x_kernel<<<(nt4 + 255) / 256, 256, 0, stream>>>(Gu, Gi, x0, nu4, nt4);
  dot_kernel<<<(B + 3) / 4, 256, 0, stream>>>(x0, user, pos, out, B, NU, 0);

  float* xc = x0;
  float* xn = x1;
  for (int l = 0; l < 3; ++l) {
    layer_kernel<<<768, 256, 0, stream>>>(xc, xn, W1 + l * 4096, b1 + l * 64,
                                          W2 + l * 4096, b2 + l * 64, startsA,
                                          counts, cw, ssrc, sw, N);
    dot_kernel<<<(B + 3) / 4, 256, 0, stream>>>(xn, user, pos, out, B, NU, 1);
    float* t = xc;
    xc = xn;
    xn = t;
  }
}

// Round 6
// 927.664 us; speedup vs baseline: 1.7586x; 1.7586x over previous
//
#include <hip/hip_runtime.h>

// ---------------------------------------------------------------------------
// NGCF forward, algebraically refactored:
//   per layer: S[v] = sum_{e: dst=v} w_e * x[src_e],  c[v] = sum w_e
//   out[v] = leakyrelu( (S+x)@W1 + (x*S)@W2 + (c+1)*b1 + c*b2 ), row-L2-norm
//   xui[b] = sum_l dot(x_l[user_b], x_l[NUM_USERS+pos_b])
// Edge buckets (CSR by dst) built once per call via multi-block counting sort.
// Layer gather: per-bucket edge metadata loaded once by all 64 lanes, then
// v_readlane broadcast -> no per-round metadata latency in the gather chain.
// ---------------------------------------------------------------------------

#define SCAN_TILE 4096  // 256 threads x 16 elems

__global__ __launch_bounds__(256) void init_x_kernel(
    const float* __restrict__ Gu, const float* __restrict__ Gi,
    float* __restrict__ x, int nu4, int nt4) {
  int i = blockIdx.x * 256 + threadIdx.x;
  if (i >= nt4) return;
  float4 v = (i < nu4) ? ((const float4*)Gu)[i] : ((const float4*)Gi)[i - nu4];
  ((float4*)x)[i] = v;
}

__global__ __launch_bounds__(256) void hist_kernel(
    const int* __restrict__ dst, int* __restrict__ counts, int E) {
  int e = blockIdx.x * 256 + threadIdx.x;
  if (e >= E) return;
  atomicAdd(&counts[dst[e]], 1);
}

// phase 1: per-tile sums
__global__ __launch_bounds__(256) void tile_sum_kernel(
    const int* __restrict__ counts, int* __restrict__ tsum, int n) {
  int tid = threadIdx.x;
  int lo = blockIdx.x * SCAN_TILE + tid * 16;
  int s = 0;
  if (lo + 16 <= n) {
    const int4* p = (const int4*)(counts + lo);
#pragma unroll
    for (int q = 0; q < 4; ++q) {
      int4 v = p[q];
      s += v.x + v.y + v.z + v.w;
    }
  } else {
    for (int i = lo; i < n && i < lo + 16; ++i) s += counts[i];
  }
#pragma unroll
  for (int m = 1; m < 64; m <<= 1) s += __shfl_xor(s, m, 64);
  __shared__ int red[4];
  if ((tid & 63) == 0) red[tid >> 6] = s;
  __syncthreads();
  if (tid == 0) tsum[blockIdx.x] = red[0] + red[1] + red[2] + red[3];
}

// phase 2: exclusive scan of tile sums (ntiles <= 64 -> one wave)
__global__ __launch_bounds__(64) void tile_scan_kernel(int* __restrict__ tsum,
                                                       int ntiles) {
  int lane = threadIdx.x;
  if (ntiles <= 64) {
    int v = (lane < ntiles) ? tsum[lane] : 0;
    int incl = v;
#pragma unroll
    for (int m = 1; m < 64; m <<= 1) {
      int t = __shfl_up(incl, m, 64);
      if (lane >= m) incl += t;
    }
    if (lane < ntiles) tsum[lane] = incl - v;
  } else if (lane == 0) {  // fallback, not expected at these sizes
    int run = 0;
    for (int i = 0; i < ntiles; ++i) {
      int t = tsum[i];
      tsum[i] = run;
      run += t;
    }
  }
}

// phase 3: per-tile exclusive scan + global offset -> starts, cursor
__global__ __launch_bounds__(256) void tile_write_kernel(
    const int* __restrict__ counts, const int* __restrict__ tsum,
    int* __restrict__ starts, int* __restrict__ cursor, int n) {
  int tid = threadIdx.x;
  int lo = blockIdx.x * SCAN_TILE + tid * 16;
  int c[16];
  int s = 0;
#pragma unroll
  for (int q = 0; q < 16; ++q) {
    int i = lo + q;
    int v = (i < n) ? counts[i] : 0;
    c[q] = v;
    s += v;
  }
  __shared__ int bs[256];
  bs[tid] = s;
  __syncthreads();
  int incl = s;
  for (int off = 1; off < 256; off <<= 1) {
    int t = (tid >= off) ? bs[tid - off] : 0;
    __syncthreads();
    incl += t;
    bs[tid] = incl;
    __syncthreads();
  }
  int run = tsum[blockIdx.x] + incl - s;
#pragma unroll
  for (int q = 0; q < 16; ++q) {
    int i = lo + q;
    if (i < n) {
      starts[i] = run;
      cursor[i] = run;
      run += c[q];
    }
  }
}

__global__ __launch_bounds__(256) void place_kernel(
    const int* __restrict__ src, const int* __restrict__ dst,
    const float* __restrict__ w, int* __restrict__ cursor,
    int* __restrict__ ssrc, float* __restrict__ sw, int E) {
  int e = blockIdx.x * 256 + threadIdx.x;
  if (e >= E) return;
  int p = atomicAdd(&cursor[dst[e]], 1);
  ssrc[p] = src[e];
  sw[p] = w[e];
}

// one wave per batch element; lane = dim; accumulate per-layer dot into out
__global__ __launch_bounds__(256) void dot_kernel(
    const float* __restrict__ x, const int* __restrict__ user,
    const int* __restrict__ pos, float* __restrict__ out,
    int batch, int nusers, int accumulate) {
  int b = blockIdx.x * 4 + (threadIdx.x >> 6);
  int lane = threadIdx.x & 63;
  if (b >= batch) return;
  int u = user[b];
  int p = nusers + pos[b];
  float val = x[u * 64 + lane] * x[p * 64 + lane];
#pragma unroll
  for (int m = 1; m < 64; m <<= 1) val += __shfl_xor(val, m, 64);
  if (lane == 0) out[b] = accumulate ? (out[b] + val) : val;
}

// fused: gather-sum S (CSR buckets, metadata broadcast via readlane),
// matvec with W cols in VGPRs, leaky-relu, row L2 normalize.
// wave per node, lane = dim.
__global__ __launch_bounds__(256) void layer_kernel(
    const float* __restrict__ xc, float* __restrict__ xn,
    const float* __restrict__ W1, const float* __restrict__ b1,
    const float* __restrict__ W2, const float* __restrict__ b2,
    const int* __restrict__ starts, const int* __restrict__ degs,
    const int* __restrict__ ssrc, const float* __restrict__ sw, int nnodes) {
  const int lane = threadIdx.x & 63;
  const int wid = threadIdx.x >> 6;
  __shared__ float ash[4][64];
  __shared__ float gsh[4][64];

  // lane k holds column k of W1 and W2 (register-resident weights)
  float w1c[64], w2c[64];
#pragma unroll
  for (int j = 0; j < 64; ++j) {
    w1c[j] = W1[j * 64 + lane];
    w2c[j] = W2[j * 64 + lane];
  }
  const float b1k = b1[lane];
  const float b2k = b2[lane];

  const int wstride = gridDim.x * 4;
  for (int v = blockIdx.x * 4 + wid; v < nnodes; v += wstride) {
    const float xk = xc[v * 64 + lane];
    int s0 = __builtin_amdgcn_readfirstlane(starts[v]);
    int dg = __builtin_amdgcn_readfirstlane(degs[v]);
    int nl = dg < 64 ? dg : 64;

    // one cooperative metadata load covers the whole bucket (deg<=64 path)
    int myidx = 0;
    float myw = 0.f;
    if (lane < nl) {
      myidx = ssrc[s0 + lane] * 64;
      myw = sw[s0 + lane];
    }
    // c[v] = sum of edge weights: butterfly reduce (lanes >= nl hold 0)
    float wsum = myw;
#pragma unroll
    for (int m = 1; m < 64; m <<= 1) wsum += __shfl_xor(wsum, m, 64);

    float S = 0.f;
    int j = 0;
    for (; j + 8 <= nl; j += 8) {
      float vv[8], ww[8];
#pragma unroll
      for (int q = 0; q < 8; ++q) {
        int a = __builtin_amdgcn_readlane(myidx, j + q);  // scalar addr
        ww[q] = __uint_as_float(
            __builtin_amdgcn_readlane(__float_as_uint(myw), j + q));
        vv[q] = xc[a + lane];  // 8 independent gathers in flight
      }
#pragma unroll
      for (int q = 0; q < 8; ++q) S = fmaf(ww[q], vv[q], S);
    }
    for (; j < nl; ++j) {
      int a = __builtin_amdgcn_readlane(myidx, j);
      float w = __uint_as_float(
          __builtin_amdgcn_readlane(__float_as_uint(myw), j));
      S = fmaf(w, xc[a + lane], S);
    }
    // rare tail: degree > 64 (direct loads, also accumulate wsum)
    for (int e = s0 + 64; e < s0 + dg; ++e) {
      float w = sw[e];
      wsum += w;
      S = fmaf(w, xc[ssrc[e] * 64 + lane], S);
    }

    ash[wid][lane] = S + xk;
    gsh[wid][lane] = S * xk;
    asm volatile("" ::: "memory");  // order LDS write before b128 reads

    float acc1 = 0.f, acc2 = 0.f;
#pragma unroll
    for (int q = 0; q < 16; ++q) {
      float4 av, gv;
      __builtin_memcpy(&av, &ash[wid][4 * q], 16);  // broadcast ds_read_b128
      __builtin_memcpy(&gv, &gsh[wid][4 * q], 16);
      acc1 = fmaf(av.x, w1c[4 * q + 0], acc1);
      acc1 = fmaf(av.y, w1c[4 * q + 1], acc1);
      acc1 = fmaf(av.z, w1c[4 * q + 2], acc1);
      acc1 = fmaf(av.w, w1c[4 * q + 3], acc1);
      acc2 = fmaf(gv.x, w2c[4 * q + 0], acc2);
      acc2 = fmaf(gv.y, w2c[4 * q + 1], acc2);
      acc2 = fmaf(gv.z, w2c[4 * q + 2], acc2);
      acc2 = fmaf(gv.w, w2c[4 * q + 3], acc2);
    }
    const float cv = wsum;
    float pre = acc1 + acc2 + (cv + 1.0f) * b1k + cv * b2k;
    float o = (pre > 0.0f) ? pre : 0.01f * pre;  // leaky relu, slope 0.01
    float ss = o * o;
#pragma unroll
    for (int m = 1; m < 64; m <<= 1) ss += __shfl_xor(ss, m, 64);
    float nrm = sqrtf(ss);
    xn[v * 64 + lane] = o / fmaxf(nrm, 1e-12f);
  }
}

extern "C" void kernel_launch(void* const* d_in, const int* in_sizes, int n_in,
                              void* d_out, int out_size, void* d_ws, size_t ws_size,
                              hipStream_t stream) {
  const float* Gu = (const float*)d_in[0];
  const float* Gi = (const float*)d_in[1];
  const float* W1 = (const float*)d_in[2];
  const float* b1 = (const float*)d_in[3];
  const float* W2 = (const float*)d_in[4];
  const float* b2 = (const float*)d_in[5];
  const float* ew = (const float*)d_in[6];
  const int* esrc = (const int*)d_in[7];
  const int* edst = (const int*)d_in[8];
  const int* user = (const int*)d_in[9];
  const int* pos = (const int*)d_in[10];
  float* out = (float*)d_out;

  const int NU = in_sizes[0] / 64;
  const int NI = in_sizes[1] / 64;
  const int N = NU + NI;
  const int E = in_sizes[6];
  const int B = in_sizes[9];

  char* ws = (char*)d_ws;
  size_t off = 0;
  auto carve = [&](size_t bytes) -> void* {
    void* p = ws + off;
    off = (off + bytes + 255) & ~(size_t)255;
    return p;
  };
  float* x0 = (float*)carve((size_t)N * 64 * 4);
  float* x1 = (float*)carve((size_t)N * 64 * 4);
  int* ssrc = (int*)carve((size_t)E * 4);
  float* sw = (float*)carve((size_t)E * 4);
  int* startsA = (int*)carve((size_t)N * 4);
  int* cursor = (int*)carve((size_t)N * 4);
  int* counts = (int*)carve((size_t)N * 4);
  const int ntiles = (N + SCAN_TILE - 1) / SCAN_TILE;
  int* tsum = (int*)carve((size_t)ntiles * 4);

  hipMemsetAsync(counts, 0, (size_t)N * 4, stream);

  hist_kernel<<<(E + 255) / 256, 256, 0, stream>>>(edst, counts, E);
  tile_sum_kernel<<<ntiles, 256, 0, stream>>>(counts, tsum, N);
  tile_scan_kernel<<<1, 64, 0, stream>>>(tsum, ntiles);
  tile_write_kernel<<<ntiles, 256, 0, stream>>>(counts, tsum, startsA, cursor, N);
  place_kernel<<<(E + 255) / 256, 256, 0, stream>>>(esrc, edst, ew, cursor, ssrc, sw, E);

  int nt4 = N * 64 / 4;
  int nu4 = NU * 64 / 4;
  init_x_kernel<<<(nt4 + 255) / 256, 256, 0, stream>>>(Gu, Gi, x0, nu4, nt4);
  dot_kernel<<<(B + 3) / 4, 256, 0, stream>>>(x0, user, pos, out, B, NU, 0);

  float* xc = x0;
  float* xn = x1;
  for (int l = 0; l < 3; ++l) {
    layer_kernel<<<768, 256, 0, stream>>>(xc, xn, W1 + l * 4096, b1 + l * 64,
                                          W2 + l * 4096, b2 + l * 64, startsA,
                                          counts, ssrc, sw, N);
    dot_kernel<<<(B + 3) / 4, 256, 0, stream>>>(xn, user, pos, out, B, NU, 1);
    float* t = xc;
    xc = xn;
    xn = t;
  }
}